// Round 5
// baseline (497.252 us; speedup 1.0000x reference)
//
#include <hip/hip_runtime.h>
#include <cstdint>

#define B_   64
#define H_   56
#define W_   56
#define C_   128
#define WSZ  7
#define TT   49
#define NN   3136            // H*W
#define MM   (B_ * NN)       // 200704
#define SCALE 0.17677669529663687f

typedef short bf16x8 __attribute__((ext_vector_type(8)));   // 8 bf16 (4 VGPRs)
typedef short bf16x4 __attribute__((ext_vector_type(4)));   // 8B (2 VGPRs)
typedef float f32x4  __attribute__((ext_vector_type(4)));
typedef unsigned short u16;

__device__ __forceinline__ float bf2f(u16 u) {
    return __uint_as_float(((unsigned int)u) << 16);
}
__device__ __forceinline__ u16 f2bf(float f) {
    unsigned int u = __float_as_uint(f);
    u += 0x7FFFu + ((u >> 16) & 1u);   // round-to-nearest-even
    return (u16)(u >> 16);
}

// ---------------------------------------------------------------------------
// KW: one-shot f32 -> bf16 weight conversion into workspace tail.
//   wqbf[384*128]: w_qkv rows, with SCALE folded into the q rows (<128)
//   wpbf[128*128]: w_proj
// ---------------------------------------------------------------------------
__global__ __launch_bounds__(256) void kw_cvt(
    const float* __restrict__ wqkv, const float* __restrict__ wproj,
    u16* __restrict__ wqbf, u16* __restrict__ wpbf)
{
    int g = blockIdx.x * 256 + threadIdx.x;      // 16384 float4 groups
    if (g < 12288) {                             // w_qkv: 49152 elems
        float4 f = *(const float4*)&wqkv[g * 4];
        float mul = (g < 4096) ? SCALE : 1.0f;   // q rows get SCALE folded
        ushort4 u;
        u.x = f2bf(f.x * mul); u.y = f2bf(f.y * mul);
        u.z = f2bf(f.z * mul); u.w = f2bf(f.w * mul);
        *(ushort4*)&wqbf[g * 4] = u;
    } else {                                     // w_proj: 16384 elems
        int g2 = g - 12288;
        float4 f = *(const float4*)&wproj[g2 * 4];
        ushort4 u;
        u.x = f2bf(f.x); u.y = f2bf(f.y);
        u.z = f2bf(f.z); u.w = f2bf(f.w);
        *(ushort4*)&wpbf[g2 * 4] = u;
    }
}

// ---------------------------------------------------------------------------
// KA v4 (unchanged from round 3 -- proven at 147 us): fused qkv-GEMM +
// windowed attention, MFMA. One block per (b,window). 3 LDS slabs, 3 blk/CU.
// ---------------------------------------------------------------------------
template <bool PREW>
__global__ __launch_bounds__(256, 3) void ka_fused(
    const float* __restrict__ x, const float* __restrict__ wqkv,
    const u16* __restrict__ wqbf,
    u16* __restrict__ vout, float* __restrict__ out)
{
    __shared__ u16 lds[26240];                       // 52,480 B
    u16 (*xq)[136] = (u16(*)[136])&lds[0];           // x, later q
    u16 (*ks)[136] = (u16(*)[136])&lds[8704];        // k
    u16 (*vs)[138] = (u16(*)[138])&lds[17408];       // v
    u16* ps_ = &lds[0];                              // P: 256 x 68 u16 overlay

    const int t   = threadIdx.x;
    const int blk = blockIdx.x;
    const int b_  = blk >> 6, wr = blk & 63;
    const int qy  = wr >> 3, qx = wr & 7;
    const int wave = t >> 6, lane = t & 63, lr = lane & 15, quad = lane >> 4;

    // ---- phase 0: stage x window -> xq (bf16), zero pad rows ----
    for (int i = t; i < 64 * 32; i += 256) {
        int tok = i >> 5, c4 = (i & 31) * 4;
        ushort4 u4 = {0, 0, 0, 0};
        if (tok < TT) {
            int hh = qy * WSZ + tok / WSZ, ww = qx * WSZ + tok % WSZ;
            float4 f = *(const float4*)&x[((size_t)b_ * NN + hh * W_ + ww) * C_ + c4];
            u4.x = f2bf(f.x); u4.y = f2bf(f.y);
            u4.z = f2bf(f.z); u4.w = f2bf(f.w);
        }
        *(ushort4*)&xq[tok][c4] = u4;
    }
    __syncthreads();

    // ---- phase 1a: k (ch=1) -> ks, v (ch=2) -> vs + global. ----
#pragma unroll
    for (int cc = 0; cc < 2; cc++) {
        const int ch = 1 + cc;
        u16* dstbase = cc ? &vs[0][0] : &ks[0][0];
        const int dstride = cc ? 138 : 136;
#pragma unroll
        for (int half = 0; half < 2; half++) {
            const int wrowi = ch * 128 + half * 64 + wave * 16 + lr;
            const float* wrowf = &wqkv[(size_t)wrowi * C_];
            const u16*   wrowb = &wqbf[(size_t)wrowi * C_];
            f32x4 acc[4];
#pragma unroll
            for (int mi = 0; mi < 4; mi++) acc[mi] = {0.f, 0.f, 0.f, 0.f};
#pragma unroll
            for (int kk = 0; kk < 4; kk++) {
                bf16x8 bfr;
                if constexpr (PREW) {
                    bfr = *(const bf16x8*)&wrowb[kk * 32 + quad * 8];
                } else {
                    float4 f0 = *(const float4*)&wrowf[kk * 32 + quad * 8];
                    float4 f1 = *(const float4*)&wrowf[kk * 32 + quad * 8 + 4];
                    bfr[0] = (short)f2bf(f0.x); bfr[1] = (short)f2bf(f0.y);
                    bfr[2] = (short)f2bf(f0.z); bfr[3] = (short)f2bf(f0.w);
                    bfr[4] = (short)f2bf(f1.x); bfr[5] = (short)f2bf(f1.y);
                    bfr[6] = (short)f2bf(f1.z); bfr[7] = (short)f2bf(f1.w);
                }
#pragma unroll
                for (int mi = 0; mi < 4; mi++) {
                    bf16x8 afr = *(const bf16x8*)&xq[mi * 16 + lr][kk * 32 + quad * 8];
                    acc[mi] = __builtin_amdgcn_mfma_f32_16x16x32_bf16(
                        afr, bfr, acc[mi], 0, 0, 0);
                }
            }
#pragma unroll
            for (int mi = 0; mi < 4; mi++) {
#pragma unroll
                for (int r = 0; r < 4; r++) {
                    int tok = mi * 16 + quad * 4 + r;
                    int col = half * 64 + wave * 16 + lr;
                    u16 bv = f2bf(acc[mi][r]);
                    dstbase[tok * dstride + col] = bv;
                    if (cc == 1 && tok < TT) {
                        int hh2 = qy * WSZ + tok / WSZ;
                        int ww2 = qx * WSZ + tok % WSZ;
                        vout[((size_t)b_ * NN + hh2 * W_ + ww2) * C_ + col] = bv;
                    }
                }
            }
        }
    }

    // ---- phase 1b: q accumulators in registers (x still live) ----
    const float qmul = PREW ? 1.0f : SCALE;      // SCALE folded into wqbf
    f32x4 qacc[2][4];
#pragma unroll
    for (int half = 0; half < 2; half++)
#pragma unroll
        for (int mi = 0; mi < 4; mi++) qacc[half][mi] = {0.f, 0.f, 0.f, 0.f};
#pragma unroll
    for (int half = 0; half < 2; half++) {
        const int wrowi = half * 64 + wave * 16 + lr;
        const float* wrowf = &wqkv[(size_t)wrowi * C_];
        const u16*   wrowb = &wqbf[(size_t)wrowi * C_];
#pragma unroll
        for (int kk = 0; kk < 4; kk++) {
            bf16x8 bfr;
            if constexpr (PREW) {
                bfr = *(const bf16x8*)&wrowb[kk * 32 + quad * 8];
            } else {
                float4 f0 = *(const float4*)&wrowf[kk * 32 + quad * 8];
                float4 f1 = *(const float4*)&wrowf[kk * 32 + quad * 8 + 4];
                bfr[0] = (short)f2bf(f0.x); bfr[1] = (short)f2bf(f0.y);
                bfr[2] = (short)f2bf(f0.z); bfr[3] = (short)f2bf(f0.w);
                bfr[4] = (short)f2bf(f1.x); bfr[5] = (short)f2bf(f1.y);
                bfr[6] = (short)f2bf(f1.z); bfr[7] = (short)f2bf(f1.w);
            }
#pragma unroll
            for (int mi = 0; mi < 4; mi++) {
                bf16x8 afr = *(const bf16x8*)&xq[mi * 16 + lr][kk * 32 + quad * 8];
                qacc[half][mi] = __builtin_amdgcn_mfma_f32_16x16x32_bf16(
                    afr, bfr, qacc[half][mi], 0, 0, 0);
            }
        }
    }
    __syncthreads();   // all x reads done; k/v published

    // write q (scaled) over the x slab
#pragma unroll
    for (int half = 0; half < 2; half++)
#pragma unroll
        for (int mi = 0; mi < 4; mi++)
#pragma unroll
            for (int r = 0; r < 4; r++)
                xq[mi * 16 + quad * 4 + r][half * 64 + wave * 16 + lr] =
                    f2bf(qacc[half][mi][r] * qmul);
    __syncthreads();   // q published

    // ---- phase 2: attention, wave = head ----
    const int h = wave;
    bf16x8 qf[4], kf[4];
#pragma unroll
    for (int mi = 0; mi < 4; mi++) {
        qf[mi] = *(const bf16x8*)&xq[mi * 16 + lr][h * 32 + quad * 8];
        kf[mi] = *(const bf16x8*)&ks[mi * 16 + lr][h * 32 + quad * 8];
    }
    __syncthreads();   // all waves hold q/k frags -> ps overlay now safe

    f32x4 s[4][4];
#pragma unroll
    for (int mi = 0; mi < 4; mi++)
#pragma unroll
        for (int nj = 0; nj < 4; nj++) s[mi][nj] = {0.f, 0.f, 0.f, 0.f};
#pragma unroll
    for (int mi = 0; mi < 4; mi++)
#pragma unroll
        for (int nj = 0; nj < 4; nj++)
            s[mi][nj] = __builtin_amdgcn_mfma_f32_16x16x32_bf16(
                qf[mi], kf[nj], s[mi][nj], 0, 0, 0);

    // mask pad key columns j = 48 + lr, lr >= 1
    if (lr >= 1) {
#pragma unroll
        for (int mi = 0; mi < 4; mi++)
#pragma unroll
            for (int r = 0; r < 4; r++) s[mi][3][r] = -1e30f;
    }

    float rsum[4][4];
#pragma unroll
    for (int mi = 0; mi < 4; mi++) {
#pragma unroll
        for (int r = 0; r < 4; r++) {
            float mx = fmaxf(fmaxf(s[mi][0][r], s[mi][1][r]),
                             fmaxf(s[mi][2][r], s[mi][3][r]));
#pragma unroll
            for (int off = 1; off < 16; off <<= 1)
                mx = fmaxf(mx, __shfl_xor(mx, off));
            float sum = 0.f;
#pragma unroll
            for (int nj = 0; nj < 4; nj++) {
                float p = __expf(s[mi][nj][r] - mx);
                s[mi][nj][r] = p;
                sum += p;
            }
#pragma unroll
            for (int off = 1; off < 16; off <<= 1)
                sum += __shfl_xor(sum, off);
            rsum[mi][r] = sum;
        }
    }

    // P: C-layout -> LDS (overlay, stride 68 = conflict-free) -> A-layout
#pragma unroll
    for (int mi = 0; mi < 4; mi++)
#pragma unroll
        for (int nj = 0; nj < 4; nj++)
#pragma unroll
            for (int r = 0; r < 4; r++)
                ps_[((h * 64) + mi * 16 + quad * 4 + r) * 68 + nj * 16 + lr] =
                    f2bf(s[mi][nj][r]);

    f32x4 o[4][2];
#pragma unroll
    for (int mi = 0; mi < 4; mi++)
#pragma unroll
        for (int nv = 0; nv < 2; nv++) o[mi][nv] = {0.f, 0.f, 0.f, 0.f};

#pragma unroll
    for (int kt = 0; kt < 2; kt++) {
        bf16x8 pf[4];
#pragma unroll
        for (int mi = 0; mi < 4; mi++) {
            const u16* pp = &ps_[((h * 64) + mi * 16 + lr) * 68 + kt * 32 + quad * 8];
            bf16x4 lo = *(const bf16x4*)&pp[0];    // 8B-aligned (rows stride 136B)
            bf16x4 hi = *(const bf16x4*)&pp[4];
            bf16x8 f;
            f[0] = lo[0]; f[1] = lo[1]; f[2] = lo[2]; f[3] = lo[3];
            f[4] = hi[0]; f[5] = hi[1]; f[6] = hi[2]; f[7] = hi[3];
            pf[mi] = f;
        }
        bf16x8 vf[2];
#pragma unroll
        for (int nv = 0; nv < 2; nv++) {
            bf16x8 tmp;
#pragma unroll
            for (int jj = 0; jj < 8; jj++)
                tmp[jj] = (short)vs[kt * 32 + quad * 8 + jj][h * 32 + nv * 16 + lr];
            vf[nv] = tmp;
        }
#pragma unroll
        for (int mi = 0; mi < 4; mi++)
#pragma unroll
            for (int nv = 0; nv < 2; nv++)
                o[mi][nv] = __builtin_amdgcn_mfma_f32_16x16x32_bf16(
                    pf[mi], vf[nv], o[mi][nv], 0, 0, 0);
    }

#pragma unroll
    for (int mi = 0; mi < 4; mi++) {
#pragma unroll
        for (int r = 0; r < 4; r++) {
            int i = mi * 16 + quad * 4 + r;
            if (i < TT) {
                int hh = qy * WSZ + i / WSZ, ww = qx * WSZ + i % WSZ;
                size_t orow = (size_t)b_ * NN + hh * W_ + ww;
                float inv = 1.f / rsum[mi][r];
#pragma unroll
                for (int nv = 0; nv < 2; nv++)
                    out[orow * C_ + h * 32 + nv * 16 + lr] = o[mi][nv][r] * inv;
            }
        }
    }
}

// ---------------------------------------------------------------------------
// KC v2: out = (y + LIM(v)) @ w_proj^T + b_proj  -- kb fused into A-staging.
// LIM = depthwise 3x3 conv (bf16 v image, f32 weights/bias), computed in f32
// during staging, before the single f2bf (same rounding path as the old
// kb->kc sequence). Eliminates kb's 205.6 MB of out read+write traffic.
// Per thread: staged column group (t&15)*4 is CONSTANT -> 36 conv weights +
// 4 biases load once per kt into statically-indexed registers; 9 tap loads
// are bf16x4, 16 consecutive lanes share a position -> coalesced 128 B.
// ---------------------------------------------------------------------------
template <bool PREW>
__global__ __launch_bounds__(256) void kc_proj(
    float* __restrict__ y, const u16* __restrict__ v,
    const float* __restrict__ wlim, const float* __restrict__ blim,
    const float* __restrict__ wproj, const u16* __restrict__ wpbf,
    const float* __restrict__ bproj)
{
    __shared__ u16 As[128][72];
    __shared__ u16 Ws[128][72];
    const int t    = threadIdx.x;
    const int m0   = blockIdx.x * 128;
    const int wave = t >> 6, lane = t & 63, lr = lane & 15, quad = lane >> 4;
    const int wm = (wave >> 1) * 64, wn = (wave & 1) * 64;
    const int colc = (t & 15) * 4;                 // per-thread staged cols

    f32x4 acc[4][4];
#pragma unroll
    for (int mi = 0; mi < 4; mi++)
#pragma unroll
        for (int ni = 0; ni < 4; ni++) acc[mi][ni] = {0.f, 0.f, 0.f, 0.f};

#pragma unroll
    for (int kt = 0; kt < 2; kt++) {
        const int k0 = kt * 64;
        const int c0 = k0 + colc;                  // 4 channels this thread stages

        // LIM weights for channels c0..c0+3 (36 contiguous f32) + bias
        float wl[36];
        {
            const float* wp = &wlim[c0 * 9];
#pragma unroll
            for (int i = 0; i < 9; i++) {
                float4 f = *(const float4*)&wp[i * 4];
                wl[i * 4 + 0] = f.x; wl[i * 4 + 1] = f.y;
                wl[i * 4 + 2] = f.z; wl[i * 4 + 3] = f.w;
            }
        }
        float4 bl = *(const float4*)&blim[c0];

        // ---- A-staging: z = y + bias + conv taps, then f2bf ----
#pragma unroll
        for (int p = 0; p < 8; p++) {
            int row = p * 16 + (t >> 4);
            int pos = m0 + row;
            int b_  = pos / NN;
            int rem = pos - b_ * NN;
            int hh  = rem / W_;
            int ww  = rem - hh * W_;

            float4 fa = *(const float4*)&y[(size_t)pos * C_ + c0];
            float z0 = fa.x + bl.x, z1 = fa.y + bl.y;
            float z2 = fa.z + bl.z, z3 = fa.w + bl.w;

            const u16* vb = &v[(size_t)b_ * NN * C_ + c0];
#pragma unroll
            for (int dy = -1; dy <= 1; dy++) {
                int yy = hh + dy;
                bool yok = (unsigned)yy < (unsigned)H_;
#pragma unroll
                for (int dx = -1; dx <= 1; dx++) {
                    int x2 = ww + dx;
                    bool ok = yok && ((unsigned)x2 < (unsigned)W_);
                    bf16x4 vv = {0, 0, 0, 0};
                    if (ok) vv = *(const bf16x4*)&vb[(size_t)(yy * W_ + x2) * C_];
                    const int tap = (dy + 1) * 3 + (dx + 1);
                    z0 += bf2f((u16)vv[0]) * wl[0 * 9 + tap];
                    z1 += bf2f((u16)vv[1]) * wl[1 * 9 + tap];
                    z2 += bf2f((u16)vv[2]) * wl[2 * 9 + tap];
                    z3 += bf2f((u16)vv[3]) * wl[3 * 9 + tap];
                }
            }
            ushort4 ua;
            ua.x = f2bf(z0); ua.y = f2bf(z1);
            ua.z = f2bf(z2); ua.w = f2bf(z3);
            *(ushort4*)&As[row][colc] = ua;
        }

        // ---- W-staging ----
        if constexpr (PREW) {
#pragma unroll
            for (int p4 = 0; p4 < 4; p4++) {
                int e    = p4 * 256 + t;
                int row  = e >> 3;
                int col8 = (e & 7) * 8;
                *(bf16x8*)&Ws[row][col8] =
                    *(const bf16x8*)&wpbf[(size_t)row * C_ + k0 + col8];
            }
        } else {
#pragma unroll
            for (int p = 0; p < 8; p++) {
                int e   = p * 256 + t;
                int row = e >> 4;
                float4 fw = *(const float4*)&wproj[(size_t)row * C_ + k0 + colc];
                ushort4 uw;
                uw.x = f2bf(fw.x); uw.y = f2bf(fw.y);
                uw.z = f2bf(fw.z); uw.w = f2bf(fw.w);
                *(ushort4*)&Ws[row][colc] = uw;
            }
        }
        __syncthreads();
#pragma unroll
        for (int kk = 0; kk < 2; kk++) {
            bf16x8 a[4], b[4];
#pragma unroll
            for (int mi = 0; mi < 4; mi++)
                a[mi] = *(const bf16x8*)&As[wm + mi * 16 + lr][kk * 32 + quad * 8];
#pragma unroll
            for (int ni = 0; ni < 4; ni++)
                b[ni] = *(const bf16x8*)&Ws[wn + ni * 16 + lr][kk * 32 + quad * 8];
#pragma unroll
            for (int mi = 0; mi < 4; mi++)
#pragma unroll
                for (int ni = 0; ni < 4; ni++)
                    acc[mi][ni] = __builtin_amdgcn_mfma_f32_16x16x32_bf16(
                        a[mi], b[ni], acc[mi][ni], 0, 0, 0);
        }
        if (kt == 0) __syncthreads();
    }

#pragma unroll
    for (int mi = 0; mi < 4; mi++) {
#pragma unroll
        for (int r = 0; r < 4; r++) {
            int m = m0 + wm + mi * 16 + quad * 4 + r;
#pragma unroll
            for (int ni = 0; ni < 4; ni++) {
                int c = wn + ni * 16 + lr;
                y[(size_t)m * C_ + c] = acc[mi][ni][r] + bproj[c];
            }
        }
    }
}

extern "C" void kernel_launch(void* const* d_in, const int* in_sizes, int n_in,
                              void* d_out, int out_size, void* d_ws, size_t ws_size,
                              hipStream_t stream)
{
    const float* x     = (const float*)d_in[0];
    const float* wqkv  = (const float*)d_in[1];
    const float* wlim  = (const float*)d_in[2];
    const float* blim  = (const float*)d_in[3];
    const float* wproj = (const float*)d_in[4];
    const float* bproj = (const float*)d_in[5];
    float* out = (float*)d_out;
    u16*   v   = (u16*)d_ws;                       // 51,380,224 B bf16 image v

    const size_t vbytes = (size_t)MM * C_ * 2;     // 51,380,224 (256B-aligned)
    const size_t need   = vbytes + (49152 + 16384) * 2;   // +131,072

    if (ws_size >= need) {
        u16* wqbf = (u16*)((char*)d_ws + vbytes);
        u16* wpbf = wqbf + 49152;
        kw_cvt<<<dim3(64), 256, 0, stream>>>(wqkv, wproj, wqbf, wpbf);
        ka_fused<true><<<dim3(B_ * 64), 256, 0, stream>>>(x, wqkv, wqbf, v, out);
        kc_proj<true><<<dim3(MM / 128), 256, 0, stream>>>(
            out, v, wlim, blim, wproj, wpbf, bproj);
    } else {
        ka_fused<false><<<dim3(B_ * 64), 256, 0, stream>>>(x, wqkv, nullptr, v, out);
        kc_proj<false><<<dim3(MM / 128), 256, 0, stream>>>(
            out, v, wlim, blim, wproj, nullptr, bproj);
    }
}

// Round 6
// 380.354 us; speedup vs baseline: 1.3073x; 1.3073x over previous
//
#include <hip/hip_runtime.h>
#include <cstdint>

#define B_   64
#define H_   56
#define W_   56
#define C_   128
#define WSZ  7
#define TT   49
#define NN   3136            // H*W
#define MM   (B_ * NN)       // 200704
#define SCALE 0.17677669529663687f

typedef short bf16x8 __attribute__((ext_vector_type(8)));   // 8 bf16 (4 VGPRs)
typedef short bf16x4 __attribute__((ext_vector_type(4)));   // 8B (2 VGPRs)
typedef float f32x4  __attribute__((ext_vector_type(4)));
typedef unsigned short u16;

__device__ __forceinline__ float bf2f(u16 u) {
    return __uint_as_float(((unsigned int)u) << 16);
}
__device__ __forceinline__ u16 f2bf(float f) {
    unsigned int u = __float_as_uint(f);
    u += 0x7FFFu + ((u >> 16) & 1u);   // round-to-nearest-even
    return (u16)(u >> 16);
}

// ---------------------------------------------------------------------------
// KW: one-shot f32 -> bf16 weight conversion into workspace tail.
//   wqbf[384*128]: w_qkv rows, with SCALE folded into the q rows (<128)
//   wpbf[128*128]: w_proj
// ---------------------------------------------------------------------------
__global__ __launch_bounds__(256) void kw_cvt(
    const float* __restrict__ wqkv, const float* __restrict__ wproj,
    u16* __restrict__ wqbf, u16* __restrict__ wpbf)
{
    int g = blockIdx.x * 256 + threadIdx.x;      // 16384 float4 groups
    if (g < 12288) {                             // w_qkv: 49152 elems
        float4 f = *(const float4*)&wqkv[g * 4];
        float mul = (g < 4096) ? SCALE : 1.0f;   // q rows get SCALE folded
        ushort4 u;
        u.x = f2bf(f.x * mul); u.y = f2bf(f.y * mul);
        u.z = f2bf(f.z * mul); u.w = f2bf(f.w * mul);
        *(ushort4*)&wqbf[g * 4] = u;
    } else {                                     // w_proj: 16384 elems
        int g2 = g - 12288;
        float4 f = *(const float4*)&wproj[g2 * 4];
        ushort4 u;
        u.x = f2bf(f.x); u.y = f2bf(f.y);
        u.z = f2bf(f.z); u.w = f2bf(f.w);
        *(ushort4*)&wpbf[g2 * 4] = u;
    }
}

// ---------------------------------------------------------------------------
// KA v4 (unchanged -- proven at 147 us in round 3): fused qkv-GEMM +
// windowed attention, MFMA. One block per (b,window). 3 LDS slabs, 3 blk/CU.
// ---------------------------------------------------------------------------
template <bool PREW>
__global__ __launch_bounds__(256, 3) void ka_fused(
    const float* __restrict__ x, const float* __restrict__ wqkv,
    const u16* __restrict__ wqbf,
    u16* __restrict__ vout, float* __restrict__ out)
{
    __shared__ u16 lds[26240];                       // 52,480 B
    u16 (*xq)[136] = (u16(*)[136])&lds[0];           // x, later q
    u16 (*ks)[136] = (u16(*)[136])&lds[8704];        // k
    u16 (*vs)[138] = (u16(*)[138])&lds[17408];       // v
    u16* ps_ = &lds[0];                              // P: 256 x 68 u16 overlay

    const int t   = threadIdx.x;
    const int blk = blockIdx.x;
    const int b_  = blk >> 6, wr = blk & 63;
    const int qy  = wr >> 3, qx = wr & 7;
    const int wave = t >> 6, lane = t & 63, lr = lane & 15, quad = lane >> 4;

    // ---- phase 0: stage x window -> xq (bf16), zero pad rows ----
    for (int i = t; i < 64 * 32; i += 256) {
        int tok = i >> 5, c4 = (i & 31) * 4;
        ushort4 u4 = {0, 0, 0, 0};
        if (tok < TT) {
            int hh = qy * WSZ + tok / WSZ, ww = qx * WSZ + tok % WSZ;
            float4 f = *(const float4*)&x[((size_t)b_ * NN + hh * W_ + ww) * C_ + c4];
            u4.x = f2bf(f.x); u4.y = f2bf(f.y);
            u4.z = f2bf(f.z); u4.w = f2bf(f.w);
        }
        *(ushort4*)&xq[tok][c4] = u4;
    }
    __syncthreads();

    // ---- phase 1a: k (ch=1) -> ks, v (ch=2) -> vs + global. ----
#pragma unroll
    for (int cc = 0; cc < 2; cc++) {
        const int ch = 1 + cc;
        u16* dstbase = cc ? &vs[0][0] : &ks[0][0];
        const int dstride = cc ? 138 : 136;
#pragma unroll
        for (int half = 0; half < 2; half++) {
            const int wrowi = ch * 128 + half * 64 + wave * 16 + lr;
            const float* wrowf = &wqkv[(size_t)wrowi * C_];
            const u16*   wrowb = &wqbf[(size_t)wrowi * C_];
            f32x4 acc[4];
#pragma unroll
            for (int mi = 0; mi < 4; mi++) acc[mi] = {0.f, 0.f, 0.f, 0.f};
#pragma unroll
            for (int kk = 0; kk < 4; kk++) {
                bf16x8 bfr;
                if constexpr (PREW) {
                    bfr = *(const bf16x8*)&wrowb[kk * 32 + quad * 8];
                } else {
                    float4 f0 = *(const float4*)&wrowf[kk * 32 + quad * 8];
                    float4 f1 = *(const float4*)&wrowf[kk * 32 + quad * 8 + 4];
                    bfr[0] = (short)f2bf(f0.x); bfr[1] = (short)f2bf(f0.y);
                    bfr[2] = (short)f2bf(f0.z); bfr[3] = (short)f2bf(f0.w);
                    bfr[4] = (short)f2bf(f1.x); bfr[5] = (short)f2bf(f1.y);
                    bfr[6] = (short)f2bf(f1.z); bfr[7] = (short)f2bf(f1.w);
                }
#pragma unroll
                for (int mi = 0; mi < 4; mi++) {
                    bf16x8 afr = *(const bf16x8*)&xq[mi * 16 + lr][kk * 32 + quad * 8];
                    acc[mi] = __builtin_amdgcn_mfma_f32_16x16x32_bf16(
                        afr, bfr, acc[mi], 0, 0, 0);
                }
            }
#pragma unroll
            for (int mi = 0; mi < 4; mi++) {
#pragma unroll
                for (int r = 0; r < 4; r++) {
                    int tok = mi * 16 + quad * 4 + r;
                    int col = half * 64 + wave * 16 + lr;
                    u16 bv = f2bf(acc[mi][r]);
                    dstbase[tok * dstride + col] = bv;
                    if (cc == 1 && tok < TT) {
                        int hh2 = qy * WSZ + tok / WSZ;
                        int ww2 = qx * WSZ + tok % WSZ;
                        vout[((size_t)b_ * NN + hh2 * W_ + ww2) * C_ + col] = bv;
                    }
                }
            }
        }
    }

    // ---- phase 1b: q accumulators in registers (x still live) ----
    const float qmul = PREW ? 1.0f : SCALE;      // SCALE folded into wqbf
    f32x4 qacc[2][4];
#pragma unroll
    for (int half = 0; half < 2; half++)
#pragma unroll
        for (int mi = 0; mi < 4; mi++) qacc[half][mi] = {0.f, 0.f, 0.f, 0.f};
#pragma unroll
    for (int half = 0; half < 2; half++) {
        const int wrowi = half * 64 + wave * 16 + lr;
        const float* wrowf = &wqkv[(size_t)wrowi * C_];
        const u16*   wrowb = &wqbf[(size_t)wrowi * C_];
#pragma unroll
        for (int kk = 0; kk < 4; kk++) {
            bf16x8 bfr;
            if constexpr (PREW) {
                bfr = *(const bf16x8*)&wrowb[kk * 32 + quad * 8];
            } else {
                float4 f0 = *(const float4*)&wrowf[kk * 32 + quad * 8];
                float4 f1 = *(const float4*)&wrowf[kk * 32 + quad * 8 + 4];
                bfr[0] = (short)f2bf(f0.x); bfr[1] = (short)f2bf(f0.y);
                bfr[2] = (short)f2bf(f0.z); bfr[3] = (short)f2bf(f0.w);
                bfr[4] = (short)f2bf(f1.x); bfr[5] = (short)f2bf(f1.y);
                bfr[6] = (short)f2bf(f1.z); bfr[7] = (short)f2bf(f1.w);
            }
#pragma unroll
            for (int mi = 0; mi < 4; mi++) {
                bf16x8 afr = *(const bf16x8*)&xq[mi * 16 + lr][kk * 32 + quad * 8];
                qacc[half][mi] = __builtin_amdgcn_mfma_f32_16x16x32_bf16(
                    afr, bfr, qacc[half][mi], 0, 0, 0);
            }
        }
    }
    __syncthreads();   // all x reads done; k/v published

    // write q (scaled) over the x slab
#pragma unroll
    for (int half = 0; half < 2; half++)
#pragma unroll
        for (int mi = 0; mi < 4; mi++)
#pragma unroll
            for (int r = 0; r < 4; r++)
                xq[mi * 16 + quad * 4 + r][half * 64 + wave * 16 + lr] =
                    f2bf(qacc[half][mi][r] * qmul);
    __syncthreads();   // q published

    // ---- phase 2: attention, wave = head ----
    const int h = wave;
    bf16x8 qf[4], kf[4];
#pragma unroll
    for (int mi = 0; mi < 4; mi++) {
        qf[mi] = *(const bf16x8*)&xq[mi * 16 + lr][h * 32 + quad * 8];
        kf[mi] = *(const bf16x8*)&ks[mi * 16 + lr][h * 32 + quad * 8];
    }
    __syncthreads();   // all waves hold q/k frags -> ps overlay now safe

    f32x4 s[4][4];
#pragma unroll
    for (int mi = 0; mi < 4; mi++)
#pragma unroll
        for (int nj = 0; nj < 4; nj++) s[mi][nj] = {0.f, 0.f, 0.f, 0.f};
#pragma unroll
    for (int mi = 0; mi < 4; mi++)
#pragma unroll
        for (int nj = 0; nj < 4; nj++)
            s[mi][nj] = __builtin_amdgcn_mfma_f32_16x16x32_bf16(
                qf[mi], kf[nj], s[mi][nj], 0, 0, 0);

    // mask pad key columns j = 48 + lr, lr >= 1
    if (lr >= 1) {
#pragma unroll
        for (int mi = 0; mi < 4; mi++)
#pragma unroll
            for (int r = 0; r < 4; r++) s[mi][3][r] = -1e30f;
    }

    float rsum[4][4];
#pragma unroll
    for (int mi = 0; mi < 4; mi++) {
#pragma unroll
        for (int r = 0; r < 4; r++) {
            float mx = fmaxf(fmaxf(s[mi][0][r], s[mi][1][r]),
                             fmaxf(s[mi][2][r], s[mi][3][r]));
#pragma unroll
            for (int off = 1; off < 16; off <<= 1)
                mx = fmaxf(mx, __shfl_xor(mx, off));
            float sum = 0.f;
#pragma unroll
            for (int nj = 0; nj < 4; nj++) {
                float p = __expf(s[mi][nj][r] - mx);
                s[mi][nj][r] = p;
                sum += p;
            }
#pragma unroll
            for (int off = 1; off < 16; off <<= 1)
                sum += __shfl_xor(sum, off);
            rsum[mi][r] = sum;
        }
    }

    // P: C-layout -> LDS (overlay, stride 68 = conflict-free) -> A-layout
#pragma unroll
    for (int mi = 0; mi < 4; mi++)
#pragma unroll
        for (int nj = 0; nj < 4; nj++)
#pragma unroll
            for (int r = 0; r < 4; r++)
                ps_[((h * 64) + mi * 16 + quad * 4 + r) * 68 + nj * 16 + lr] =
                    f2bf(s[mi][nj][r]);

    f32x4 o[4][2];
#pragma unroll
    for (int mi = 0; mi < 4; mi++)
#pragma unroll
        for (int nv = 0; nv < 2; nv++) o[mi][nv] = {0.f, 0.f, 0.f, 0.f};

#pragma unroll
    for (int kt = 0; kt < 2; kt++) {
        bf16x8 pf[4];
#pragma unroll
        for (int mi = 0; mi < 4; mi++) {
            const u16* pp = &ps_[((h * 64) + mi * 16 + lr) * 68 + kt * 32 + quad * 8];
            bf16x4 lo = *(const bf16x4*)&pp[0];    // 8B-aligned (rows stride 136B)
            bf16x4 hi = *(const bf16x4*)&pp[4];
            bf16x8 f;
            f[0] = lo[0]; f[1] = lo[1]; f[2] = lo[2]; f[3] = lo[3];
            f[4] = hi[0]; f[5] = hi[1]; f[6] = hi[2]; f[7] = hi[3];
            pf[mi] = f;
        }
        bf16x8 vf[2];
#pragma unroll
        for (int nv = 0; nv < 2; nv++) {
            bf16x8 tmp;
#pragma unroll
            for (int jj = 0; jj < 8; jj++)
                tmp[jj] = (short)vs[kt * 32 + quad * 8 + jj][h * 32 + nv * 16 + lr];
            vf[nv] = tmp;
        }
#pragma unroll
        for (int mi = 0; mi < 4; mi++)
#pragma unroll
            for (int nv = 0; nv < 2; nv++)
                o[mi][nv] = __builtin_amdgcn_mfma_f32_16x16x32_bf16(
                    pf[mi], vf[nv], o[mi][nv], 0, 0, 0);
    }

#pragma unroll
    for (int mi = 0; mi < 4; mi++) {
#pragma unroll
        for (int r = 0; r < 4; r++) {
            int i = mi * 16 + quad * 4 + r;
            if (i < TT) {
                int hh = qy * WSZ + i / WSZ, ww = qx * WSZ + i % WSZ;
                size_t orow = (size_t)b_ * NN + hh * W_ + ww;
                float inv = 1.f / rsum[mi][r];
#pragma unroll
                for (int nv = 0; nv < 2; nv++)
                    out[orow * C_ + h * 32 + nv * 16 + lr] = o[mi][nv][r] * inv;
            }
        }
    }
}

// ---------------------------------------------------------------------------
// KB v3: depthwise 3x3 conv on bf16 v (IMAGE layout B,H,W,C), one thread =
// 8 channels of one position, high occupancy (8 VGPR class).
// ZOUT=true:  z = bf16(y + bias + conv)  -- 51.4 MB bf16 write instead of
//             102.8 MB f32 RMW; kc then stages A straight from z.
//             Rounding path identical to the old RMW->kc-f2bf sequence.
// ZOUT=false: legacy f32 RMW into out (round-3-proven fallback).
// ---------------------------------------------------------------------------
template <bool ZOUT>
__global__ __launch_bounds__(256) void kb_lim(
    const u16* __restrict__ v, const float* __restrict__ wlim,
    const float* __restrict__ blim, const float* __restrict__ y,
    u16* __restrict__ z, float* __restrict__ out)
{
    const int t   = threadIdx.x;
    const int pos = blockIdx.x * 16 + (t >> 4);
    const int c0  = (t & 15) * 8;
    const int b_  = pos / NN;
    const int rem = pos - b_ * NN;
    const int hh  = rem / W_;
    const int ww  = rem - hh * W_;

    float w72[72];
    {
        const float* wp = &wlim[c0 * 9];
#pragma unroll
        for (int i = 0; i < 18; i++) {
            float4 f = *(const float4*)&wp[i * 4];
            w72[i * 4 + 0] = f.x; w72[i * 4 + 1] = f.y;
            w72[i * 4 + 2] = f.z; w72[i * 4 + 3] = f.w;
        }
    }
    float acc[8];
    {
        float4 b0 = *(const float4*)&blim[c0];
        float4 b1 = *(const float4*)&blim[c0 + 4];
        acc[0] = b0.x; acc[1] = b0.y; acc[2] = b0.z; acc[3] = b0.w;
        acc[4] = b1.x; acc[5] = b1.y; acc[6] = b1.z; acc[7] = b1.w;
    }

    const u16* vbase = &v[(size_t)b_ * NN * C_ + c0];
#pragma unroll
    for (int dy = -1; dy <= 1; dy++) {
        int yy = hh + dy;
        bool yok = (unsigned)yy < (unsigned)H_;
#pragma unroll
        for (int dx = -1; dx <= 1; dx++) {
            int x2 = ww + dx;
            bool ok = yok && ((unsigned)x2 < (unsigned)W_);
            bf16x8 vv = {0, 0, 0, 0, 0, 0, 0, 0};
            if (ok) vv = *(const bf16x8*)&vbase[(size_t)(yy * W_ + x2) * C_];
            const int tap = (dy + 1) * 3 + (dx + 1);
#pragma unroll
            for (int j = 0; j < 8; j++)
                acc[j] += bf2f((u16)vv[j]) * w72[j * 9 + tap];
        }
    }

    if constexpr (ZOUT) {
        const float* yp = &y[(size_t)pos * C_ + c0];
        float4 y0 = *(const float4*)&yp[0];
        float4 y1 = *(const float4*)&yp[4];
        bf16x8 zz;
        zz[0] = (short)f2bf(y0.x + acc[0]); zz[1] = (short)f2bf(y0.y + acc[1]);
        zz[2] = (short)f2bf(y0.z + acc[2]); zz[3] = (short)f2bf(y0.w + acc[3]);
        zz[4] = (short)f2bf(y1.x + acc[4]); zz[5] = (short)f2bf(y1.y + acc[5]);
        zz[6] = (short)f2bf(y1.z + acc[6]); zz[7] = (short)f2bf(y1.w + acc[7]);
        *(bf16x8*)&z[(size_t)pos * C_ + c0] = zz;
    } else {
        float* op = &out[(size_t)pos * C_ + c0];
        float4 o0 = *(const float4*)&op[0];
        float4 o1 = *(const float4*)&op[4];
        o0.x += acc[0]; o0.y += acc[1]; o0.z += acc[2]; o0.w += acc[3];
        o1.x += acc[4]; o1.y += acc[5]; o1.z += acc[6]; o1.w += acc[7];
        *(float4*)&op[0] = o0;
        *(float4*)&op[4] = o1;
    }
}

// ---------------------------------------------------------------------------
// KC v3: out = A @ w_proj^T + b_proj, MFMA gemm_bt.
// MODE 2: A staged by direct 16B bf16 copies from z (no f32 loads, no f2bf),
//         W from precomputed wpbf.  MODE 1: A from f32 y + f2bf, W from wpbf
// (round-3-proven).  MODE 0: full f32 fallback.
// ---------------------------------------------------------------------------
template <int MODE>
__global__ __launch_bounds__(256) void kc_proj(
    float* __restrict__ y, const u16* __restrict__ z,
    const float* __restrict__ wproj, const u16* __restrict__ wpbf,
    const float* __restrict__ bproj)
{
    __shared__ u16 As[128][72];
    __shared__ u16 Ws[128][72];
    const int t    = threadIdx.x;
    const int m0   = blockIdx.x * 128;
    const int wave = t >> 6, lane = t & 63, lr = lane & 15, quad = lane >> 4;
    const int wm = (wave >> 1) * 64, wn = (wave & 1) * 64;

    f32x4 acc[4][4];
#pragma unroll
    for (int mi = 0; mi < 4; mi++)
#pragma unroll
        for (int ni = 0; ni < 4; ni++) acc[mi][ni] = {0.f, 0.f, 0.f, 0.f};

#pragma unroll
    for (int kt = 0; kt < 2; kt++) {
        const int k0 = kt * 64;

        // ---- A-staging ----
        if constexpr (MODE == 2) {
#pragma unroll
            for (int p4 = 0; p4 < 4; p4++) {
                int e    = p4 * 256 + t;
                int row  = e >> 3;
                int col8 = (e & 7) * 8;
                *(bf16x8*)&As[row][col8] =
                    *(const bf16x8*)&z[(size_t)(m0 + row) * C_ + k0 + col8];
            }
        } else {
#pragma unroll
            for (int p = 0; p < 8; p++) {
                int e   = p * 256 + t;
                int row = e >> 4;
                int col = (e & 15) * 4;
                float4 fa = *(const float4*)&y[(size_t)(m0 + row) * C_ + k0 + col];
                ushort4 ua;
                ua.x = f2bf(fa.x); ua.y = f2bf(fa.y);
                ua.z = f2bf(fa.z); ua.w = f2bf(fa.w);
                *(ushort4*)&As[row][col] = ua;
            }
        }

        // ---- W-staging ----
        if constexpr (MODE >= 1) {
#pragma unroll
            for (int p4 = 0; p4 < 4; p4++) {
                int e    = p4 * 256 + t;
                int row  = e >> 3;
                int col8 = (e & 7) * 8;
                *(bf16x8*)&Ws[row][col8] =
                    *(const bf16x8*)&wpbf[(size_t)row * C_ + k0 + col8];
            }
        } else {
#pragma unroll
            for (int p = 0; p < 8; p++) {
                int e   = p * 256 + t;
                int row = e >> 4;
                int col = (e & 15) * 4;
                float4 fw = *(const float4*)&wproj[(size_t)row * C_ + k0 + col];
                ushort4 uw;
                uw.x = f2bf(fw.x); uw.y = f2bf(fw.y);
                uw.z = f2bf(fw.z); uw.w = f2bf(fw.w);
                *(ushort4*)&Ws[row][col] = uw;
            }
        }
        __syncthreads();
#pragma unroll
        for (int kk = 0; kk < 2; kk++) {
            bf16x8 a[4], b[4];
#pragma unroll
            for (int mi = 0; mi < 4; mi++)
                a[mi] = *(const bf16x8*)&As[wm + mi * 16 + lr][kk * 32 + quad * 8];
#pragma unroll
            for (int ni = 0; ni < 4; ni++)
                b[ni] = *(const bf16x8*)&Ws[wn + ni * 16 + lr][kk * 32 + quad * 8];
#pragma unroll
            for (int mi = 0; mi < 4; mi++)
#pragma unroll
                for (int ni = 0; ni < 4; ni++)
                    acc[mi][ni] = __builtin_amdgcn_mfma_f32_16x16x32_bf16(
                        a[mi], b[ni], acc[mi][ni], 0, 0, 0);
        }
        if (kt == 0) __syncthreads();
    }

#pragma unroll
    for (int mi = 0; mi < 4; mi++) {
#pragma unroll
        for (int r = 0; r < 4; r++) {
            int m = m0 + wm + mi * 16 + quad * 4 + r;
#pragma unroll
            for (int ni = 0; ni < 4; ni++) {
                int c = wn + ni * 16 + lr;
                y[(size_t)m * C_ + c] = acc[mi][ni][r] + bproj[c];
            }
        }
    }
}

extern "C" void kernel_launch(void* const* d_in, const int* in_sizes, int n_in,
                              void* d_out, int out_size, void* d_ws, size_t ws_size,
                              hipStream_t stream)
{
    const float* x     = (const float*)d_in[0];
    const float* wqkv  = (const float*)d_in[1];
    const float* wlim  = (const float*)d_in[2];
    const float* blim  = (const float*)d_in[3];
    const float* wproj = (const float*)d_in[4];
    const float* bproj = (const float*)d_in[5];
    float* out = (float*)d_out;
    u16*   v   = (u16*)d_ws;                         // 51,380,224 B bf16 image v

    const size_t vbytes = (size_t)MM * C_ * 2;       // 51,380,224 (256B-aligned)
    const size_t wbytes = (49152 + 16384) * 2;       // 131,072
    const size_t need1  = vbytes + wbytes;           // weights path
    const size_t need2  = need1 + vbytes;            // + bf16 z intermediate

    if (ws_size >= need2) {
        u16* wqbf = (u16*)((char*)d_ws + vbytes);
        u16* wpbf = wqbf + 49152;
        u16* zbuf = (u16*)((char*)d_ws + need1);
        kw_cvt<<<dim3(64), 256, 0, stream>>>(wqkv, wproj, wqbf, wpbf);
        ka_fused<true><<<dim3(B_ * 64), 256, 0, stream>>>(x, wqkv, wqbf, v, out);
        kb_lim<true><<<dim3(MM / 16), 256, 0, stream>>>(v, wlim, blim, out, zbuf, nullptr);
        kc_proj<2><<<dim3(MM / 128), 256, 0, stream>>>(out, zbuf, nullptr, wpbf, bproj);
    } else if (ws_size >= need1) {
        u16* wqbf = (u16*)((char*)d_ws + vbytes);
        u16* wpbf = wqbf + 49152;
        kw_cvt<<<dim3(64), 256, 0, stream>>>(wqkv, wproj, wqbf, wpbf);
        ka_fused<true><<<dim3(B_ * 64), 256, 0, stream>>>(x, wqkv, wqbf, v, out);
        kb_lim<false><<<dim3(MM / 16), 256, 0, stream>>>(v, wlim, blim, nullptr, nullptr, out);
        kc_proj<1><<<dim3(MM / 128), 256, 0, stream>>>(out, nullptr, nullptr, wpbf, bproj);
    } else {
        ka_fused<false><<<dim3(B_ * 64), 256, 0, stream>>>(x, wqkv, nullptr, v, out);
        kb_lim<false><<<dim3(MM / 16), 256, 0, stream>>>(v, wlim, blim, nullptr, nullptr, out);
        kc_proj<0><<<dim3(MM / 128), 256, 0, stream>>>(out, nullptr, wproj, nullptr, bproj);
    }
}